// Round 6
// baseline (299.397 us; speedup 1.0000x reference)
//
#include <hip/hip_runtime.h>
#include <hip/hip_fp16.h>
#include <math.h>
#include <stdint.h>

#define HH 512
#define WW 512
#define NIMG 24
#define CCH 3
#define TAU 0.25f
#define TVEPS 2e-4f
#define NUMEL 262144.0f
#define NITER 10

// ws layout:
// byte 0      : pd partials, NITER x 24 x 64 floats
// byte 65536  : pn partials, NITER x 24 x 64 floats
// byte 131072 : imgh (__half, 24*512*512)
// byte 12713984: ptA (uint32 packed half2, parity 0)
// byte 37879808: ptB (parity 1)

__device__ __forceinline__ float2 h2f(uint32_t v) {
    __half2 h; *reinterpret_cast<uint32_t*>(&h) = v;
    return __half22float2(h);
}
__device__ __forceinline__ uint32_t f2h2(float a, float b) {
    __half2 h = __floats2half2_rn(a, b);
    return *reinterpret_cast<uint32_t*>(&h);
}

__device__ __forceinline__ void block_reduce_store(float v0, float v1,
                                                   float* p0, float* p1, int tid) {
    for (int off = 32; off > 0; off >>= 1) {
        v0 += __shfl_down(v0, off, 64);
        v1 += __shfl_down(v1, off, 64);
    }
    __shared__ float sr[2][4];
    int wave = tid >> 6, lane = tid & 63;
    if (lane == 0) { sr[0][wave] = v0; sr[1][wave] = v1; }
    __syncthreads();
    if (tid == 0) {
        *p0 = (sr[0][0] + sr[0][1]) + (sr[0][2] + sr[0][3]);
        *p1 = (sr[1][0] + sr[1][1]) + (sr[1][2] + sr[1][3]);
    }
}

// Iteration 0: out = img. Writes pt parity-0, imgh, partials k=0.
__global__ __launch_bounds__(256, 4) void tv_step0(
    const float* __restrict__ img, const float* __restrict__ weight,
    __half* __restrict__ imgh, uint32_t* __restrict__ ptout,
    float* __restrict__ pd, float* __restrict__ pn)
{
    const int im = blockIdx.z;
    const int bid = blockIdx.y * 8 + blockIdx.x;
    const float w = weight[im / CCH];
    const int x0 = blockIdx.x * 64, y0 = blockIdx.y * 64;
    const float* imgI = img + (size_t)im * HH * WW;
    __half* hI = imgh + (size_t)im * HH * WW;
    uint32_t* pI = ptout + (size_t)im * HH * WW;
    __shared__ float s[65][68];
    const int tid = threadIdx.x;
    const int tx = tid & 15, ry = tid >> 4;
    const int gx = x0 + 4 * tx;

    float o[4][4];
    #pragma unroll
    for (int i = 0; i < 4; ++i) {
        int ey = ry + 16 * i, gy = y0 + ey;
        float4 v = *(const float4*)(imgI + (size_t)gy * WW + gx);
        o[i][0] = v.x; o[i][1] = v.y; o[i][2] = v.z; o[i][3] = v.w;
        *(float4*)&s[ey][4 * tx] = v;
    }
    if (tx == 15 && x0 + 64 < WW) {
        #pragma unroll
        for (int i = 0; i < 4; ++i) {
            int ey = ry + 16 * i, gy = y0 + ey;
            s[ey][64] = imgI[(size_t)gy * WW + x0 + 64];
        }
    }
    if (ry == 0 && y0 + 64 < HH)
        *(float4*)&s[64][4 * tx] = *(const float4*)(imgI + (size_t)(y0 + 64) * WW + gx);
    __syncthreads();

    float accn = 0.f;
    const float tw = TAU / w;
    #pragma unroll
    for (int i = 0; i < 4; ++i) {
        int ey = ry + 16 * i, gy = y0 + ey;
        float4 dn = *(float4*)&s[ey + 1][4 * tx];
        float rt_sh = __shfl_down(o[i][0], 1, 64);
        float rt = (tx == 15) ? s[ey][64] : rt_sh;
        float dnv[4] = {dn.x, dn.y, dn.z, dn.w};
        uint32_t pv[4];
        #pragma unroll
        for (int j = 0; j < 4; ++j) {
            float ov = o[i][j];
            float g0 = (gy < HH - 1) ? dnv[j] - ov : 0.f;
            float rn = (j < 3) ? o[i][j + 1] : rt;
            float g1 = (gx + j < WW - 1) ? rn - ov : 0.f;
            float ss2 = g0 * g0 + g1 * g1;
            float nrm = (ss2 > 0.f) ? sqrtf(ss2) : 0.f;
            accn += nrm;
            float inv = 1.f / (1.f + tw * nrm);
            pv[j] = f2h2(-TAU * g0 * inv, -TAU * g1 * inv);
        }
        size_t off = (size_t)gy * WW + gx;
        *(uint4*)(pI + off) = make_uint4(pv[0], pv[1], pv[2], pv[3]);
        *(uint2*)(hI + off) = make_uint2(f2h2(o[i][0], o[i][1]), f2h2(o[i][2], o[i][3]));
    }
    block_reduce_store(0.f, accn, &pd[im * 64 + bid], &pn[im * 64 + bid], tid);
}

// Iterations 1..9: history reconstruction + TV step + partial store + out writes.
__global__ __launch_bounds__(256, 4) void tv_stepN(
    const __half* __restrict__ imgh, const float* __restrict__ weight,
    const uint32_t* __restrict__ pt_in, uint32_t* __restrict__ pt_out,
    float* __restrict__ out, float* __restrict__ pd, float* __restrict__ pn, int it)
{
    const int im = blockIdx.z;
    const int bid = blockIdx.y * 8 + blockIdx.x;
    const float w = weight[im / CCH];
    const float tw = TAU / w;
    const int x0 = blockIdx.x * 64, y0 = blockIdx.y * 64;
    const size_t ibase = (size_t)im * HH * WW;
    const __half* hI = imgh + ibase;
    const uint32_t* pinI = pt_in + ibase;
    uint32_t* poutI = pt_out + ibase;
    float* outI = out + ibase;
    const int tid = threadIdx.x;
    const int tx = tid & 15, ry = tid >> 4;
    const int gx = x0 + 4 * tx;

    // ---- deterministic history reconstruction (wave 0, fixed tree) ----
    __shared__ int sKf;
    if (tid < 64) {
        float n0 = pn[im * 64 + tid];
        for (int off = 32; off > 0; off >>= 1) n0 += __shfl_down(n0, off, 64);
        float E0 = w * __shfl(n0, 0, 64) / NUMEL;
        float Eprev = E0;
        int kf = -1;
        for (int k = 1; k < it; ++k) {
            float d = pd[k * NIMG * 64 + im * 64 + tid];
            float n = pn[k * NIMG * 64 + im * 64 + tid];
            for (int off = 32; off > 0; off >>= 1) {
                d += __shfl_down(d, off, 64);
                n += __shfl_down(n, off, 64);
            }
            float Ek = (__shfl(d, 0, 64) + w * __shfl(n, 0, 64)) / NUMEL;
            if (fabsf(Eprev - Ek) < TVEPS * E0) { kf = k; break; }
            Eprev = Ek;
        }
        if (tid == 0) sKf = kf;
    }
    __syncthreads();
    const int kf = sKf;

    if (kf >= 0) {
        if (kf == it - 1) {
            // newly frozen: out = imgh + div(pt input of iteration kf) = div(poutI buf)
            const uint32_t* pf = poutI;
            #pragma unroll
            for (int i = 0; i < 4; ++i) {
                int gy = y0 + ry + 16 * i;
                size_t off = (size_t)gy * WW + gx;
                uint4 cv = *(const uint4*)(pf + off);
                uint4 uv = make_uint4(0u, 0u, 0u, 0u);
                if (gy > 0) uv = *(const uint4*)(pf + off - WW);
                uint32_t lf = (gx > 0) ? pf[off - 1] : 0u;
                uint2 hh = *(const uint2*)(hI + off);
                float2 ia = h2f(hh.x), ib = h2f(hh.y);
                float imv[4] = {ia.x, ia.y, ib.x, ib.y};
                uint32_t cc[4] = {cv.x, cv.y, cv.z, cv.w};
                uint32_t uu[4] = {uv.x, uv.y, uv.z, uv.w};
                uint32_t lt[4] = {lf, cv.x, cv.y, cv.z};
                float r[4];
                #pragma unroll
                for (int j = 0; j < 4; ++j) {
                    float2 cf = h2f(cc[j]);
                    r[j] = imv[j] + (-(cf.x + cf.y) + h2f(uu[j]).x + h2f(lt[j]).y);
                }
                *(float4*)(outI + off) = make_float4(r[0], r[1], r[2], r[3]);
            }
        }
        return;
    }

    // ---- normal TV step ----
    __shared__ float s[65][68];
    uint32_t c[4][4];
    float o[4][4], imv4[4][4];

    #pragma unroll
    for (int i = 0; i < 4; ++i) {
        int ey = ry + 16 * i, gy = y0 + ey;
        size_t off = (size_t)gy * WW + gx;
        uint4 cv = *(const uint4*)(pinI + off);
        uint4 uv = make_uint4(0u, 0u, 0u, 0u);
        if (gy > 0) uv = *(const uint4*)(pinI + off - WW);
        uint32_t lf = (gx > 0) ? pinI[off - 1] : 0u;
        uint2 hh = *(const uint2*)(hI + off);
        c[i][0] = cv.x; c[i][1] = cv.y; c[i][2] = cv.z; c[i][3] = cv.w;
        uint32_t uu[4] = {uv.x, uv.y, uv.z, uv.w};
        uint32_t lt[4] = {lf, cv.x, cv.y, cv.z};
        float2 ia = h2f(hh.x), ib = h2f(hh.y);
        imv4[i][0] = ia.x; imv4[i][1] = ia.y; imv4[i][2] = ib.x; imv4[i][3] = ib.y;
        #pragma unroll
        for (int j = 0; j < 4; ++j) {
            float2 cf = h2f(c[i][j]);
            o[i][j] = imv4[i][j] + (-(cf.x + cf.y) + h2f(uu[j]).x + h2f(lt[j]).y);
        }
        *(float4*)&s[ey][4 * tx] = make_float4(o[i][0], o[i][1], o[i][2], o[i][3]);
    }
    if (tx == 15 && x0 + 64 < WW) {
        #pragma unroll
        for (int i = 0; i < 4; ++i) {
            int ey = ry + 16 * i, gy = y0 + ey;
            size_t off = (size_t)gy * WW + x0 + 64;
            uint32_t c2 = pinI[off];
            uint32_t u2 = (gy > 0) ? pinI[off - WW] : 0u;
            float2 cf = h2f(c2);
            s[ey][64] = __half2float(hI[off]) +
                        (-(cf.x + cf.y) + h2f(u2).x + h2f(c[i][3]).y);
        }
    }
    if (ry == 0 && y0 + 64 < HH) {
        int gy = y0 + 64;
        size_t off = (size_t)gy * WW + gx;
        uint4 cv = *(const uint4*)(pinI + off);
        uint4 uv = *(const uint4*)(pinI + off - WW);
        uint32_t lf = (gx > 0) ? pinI[off - 1] : 0u;
        uint2 hh = *(const uint2*)(hI + off);
        float2 ia = h2f(hh.x), ib = h2f(hh.y);
        float imv[4] = {ia.x, ia.y, ib.x, ib.y};
        uint32_t cc[4] = {cv.x, cv.y, cv.z, cv.w};
        uint32_t uu[4] = {uv.x, uv.y, uv.z, uv.w};
        uint32_t lt[4] = {lf, cv.x, cv.y, cv.z};
        float ob[4];
        #pragma unroll
        for (int j = 0; j < 4; ++j) {
            float2 cf = h2f(cc[j]);
            ob[j] = imv[j] + (-(cf.x + cf.y) + h2f(uu[j]).x + h2f(lt[j]).y);
        }
        *(float4*)&s[64][4 * tx] = make_float4(ob[0], ob[1], ob[2], ob[3]);
    }
    __syncthreads();

    float accd = 0.f, accn = 0.f;
    const bool last = (it == NITER - 1);
    #pragma unroll
    for (int i = 0; i < 4; ++i) {
        int ey = ry + 16 * i, gy = y0 + ey;
        float4 dn = *(float4*)&s[ey + 1][4 * tx];
        float rt_sh = __shfl_down(o[i][0], 1, 64);
        float rt = (tx == 15) ? s[ey][64] : rt_sh;
        float dnv[4] = {dn.x, dn.y, dn.z, dn.w};
        uint32_t pv[4];
        #pragma unroll
        for (int j = 0; j < 4; ++j) {
            float ov = o[i][j];
            float g0 = (gy < HH - 1) ? dnv[j] - ov : 0.f;
            float rn = (j < 3) ? o[i][j + 1] : rt;
            float g1 = (gx + j < WW - 1) ? rn - ov : 0.f;
            float ss2 = g0 * g0 + g1 * g1;
            float nrm = (ss2 > 0.f) ? sqrtf(ss2) : 0.f;
            accn += nrm;
            float dtv = ov - imv4[i][j];
            accd += dtv * dtv;
            float inv = 1.f / (1.f + tw * nrm);
            float2 cf = h2f(c[i][j]);
            pv[j] = f2h2((cf.x - TAU * g0) * inv, (cf.y - TAU * g1) * inv);
        }
        size_t off = (size_t)gy * WW + gx;
        *(uint4*)(poutI + off) = make_uint4(pv[0], pv[1], pv[2], pv[3]);
        if (last)
            *(float4*)(outI + off) = make_float4(o[i][0], o[i][1], o[i][2], o[i][3]);
    }
    block_reduce_store(accd, accn,
                       &pd[it * NIMG * 64 + im * 64 + bid],
                       &pn[it * NIMG * 64 + im * 64 + bid], tid);
}

extern "C" void kernel_launch(void* const* d_in, const int* in_sizes, int n_in,
                              void* d_out, int out_size, void* d_ws, size_t ws_size,
                              hipStream_t stream)
{
    const float* img = (const float*)d_in[0];
    const float* weight = (const float*)d_in[1];
    float* out = (float*)d_out;
    float* pd = (float*)((char*)d_ws + 0);
    float* pn = (float*)((char*)d_ws + 65536);
    __half* imgh = (__half*)((char*)d_ws + 131072);
    uint32_t* ptA = (uint32_t*)((char*)d_ws + 12713984);  // parity 0
    uint32_t* ptB = (uint32_t*)((char*)d_ws + 37879808);  // parity 1

    dim3 grid(8, 8, NIMG);
    dim3 block(256);

    tv_step0<<<grid, block, 0, stream>>>(img, weight, imgh, ptA, pd, pn);
    for (int it = 1; it < NITER; ++it) {
        uint32_t* pin  = (it & 1) ? ptA : ptB;   // parity (it-1)&1
        uint32_t* pout = (it & 1) ? ptB : ptA;   // parity it&1
        tv_stepN<<<grid, block, 0, stream>>>(imgh, weight, pin, pout, out, pd, pn, it);
    }
}

// Round 7
// 292.177 us; speedup vs baseline: 1.0247x; 1.0247x over previous
//
#include <hip/hip_runtime.h>
#include <hip/hip_fp16.h>
#include <math.h>
#include <stdint.h>

#define HH 512
#define WW 512
#define NIMG 24
#define CCH 3
#define TAU 0.25f
#define TVEPS 2e-4f
#define NUMEL 262144.0f
#define NITER 10
#define PTELEMS (NIMG * HH * WW)   // u32 elements per pt snapshot

// ws layout:
// byte 0      : pd partials, 10 x 24 x 64 floats (only k=1..8 used)
// byte 65536  : pn partials, 10 x 24 x 64 floats (k=0..8 used)
// byte 131072 : imgh (__half, 24*512*512 = 12.58 MB)
// byte 12713984: ptbuf[0..8], 9 snapshots x 25,165,824 B  (ends at 239.2 MB)

__device__ __forceinline__ float2 h2f(uint32_t v) {
    __half2 h; *reinterpret_cast<uint32_t*>(&h) = v;
    return __half22float2(h);
}
__device__ __forceinline__ uint32_t f2h2(float a, float b) {
    __half2 h = __floats2half2_rn(a, b);
    return *reinterpret_cast<uint32_t*>(&h);
}

__device__ __forceinline__ void block_reduce_store(float v0, float v1,
                                                   float* p0, float* p1, int tid) {
    for (int off = 32; off > 0; off >>= 1) {
        v0 += __shfl_down(v0, off, 64);
        v1 += __shfl_down(v1, off, 64);
    }
    __shared__ float sr[2][4];
    int wave = tid >> 6, lane = tid & 63;
    if (lane == 0) { sr[0][wave] = v0; sr[1][wave] = v1; }
    __syncthreads();
    if (tid == 0) {
        *p0 = (sr[0][0] + sr[0][1]) + (sr[0][2] + sr[0][3]);
        *p1 = (sr[1][0] + sr[1][1]) + (sr[1][2] + sr[1][3]);
    }
}

// Iteration 0: out = img. Writes ptbuf[0], imgh, partials k=0 (norm only).
__global__ __launch_bounds__(256, 4) void tv_step0(
    const float* __restrict__ img, const float* __restrict__ weight,
    __half* __restrict__ imgh, uint32_t* __restrict__ ptout,
    float* __restrict__ pd, float* __restrict__ pn)
{
    const int im = blockIdx.z;
    const int bid = blockIdx.y * 8 + blockIdx.x;
    const float w = weight[im / CCH];
    const int x0 = blockIdx.x * 64, y0 = blockIdx.y * 64;
    const float* imgI = img + (size_t)im * HH * WW;
    __half* hI = imgh + (size_t)im * HH * WW;
    uint32_t* pI = ptout + (size_t)im * HH * WW;
    __shared__ float s[65][68];
    const int tid = threadIdx.x;
    const int tx = tid & 15, ry = tid >> 4;
    const int gx = x0 + 4 * tx;

    float o[4][4];
    #pragma unroll
    for (int i = 0; i < 4; ++i) {
        int ey = ry + 16 * i, gy = y0 + ey;
        float4 v = *(const float4*)(imgI + (size_t)gy * WW + gx);
        o[i][0] = v.x; o[i][1] = v.y; o[i][2] = v.z; o[i][3] = v.w;
        *(float4*)&s[ey][4 * tx] = v;
    }
    if (tx == 15 && x0 + 64 < WW) {
        #pragma unroll
        for (int i = 0; i < 4; ++i) {
            int ey = ry + 16 * i, gy = y0 + ey;
            s[ey][64] = imgI[(size_t)gy * WW + x0 + 64];
        }
    }
    if (ry == 0 && y0 + 64 < HH)
        *(float4*)&s[64][4 * tx] = *(const float4*)(imgI + (size_t)(y0 + 64) * WW + gx);
    __syncthreads();

    float accn = 0.f;
    const float tw = TAU / w;
    #pragma unroll
    for (int i = 0; i < 4; ++i) {
        int ey = ry + 16 * i, gy = y0 + ey;
        float4 dn = *(float4*)&s[ey + 1][4 * tx];
        float rt_sh = __shfl_down(o[i][0], 1, 64);
        float rt = (tx == 15) ? s[ey][64] : rt_sh;
        float dnv[4] = {dn.x, dn.y, dn.z, dn.w};
        uint32_t pv[4];
        #pragma unroll
        for (int j = 0; j < 4; ++j) {
            float ov = o[i][j];
            float g0 = (gy < HH - 1) ? dnv[j] - ov : 0.f;
            float rn = (j < 3) ? o[i][j + 1] : rt;
            float g1 = (gx + j < WW - 1) ? rn - ov : 0.f;
            float ss2 = g0 * g0 + g1 * g1;
            float nrm = (ss2 > 0.f) ? sqrtf(ss2) : 0.f;
            accn += nrm;
            float inv = 1.f / (1.f + tw * nrm);
            pv[j] = f2h2(-TAU * g0 * inv, -TAU * g1 * inv);
        }
        size_t off = (size_t)gy * WW + gx;
        *(uint4*)(pI + off) = make_uint4(pv[0], pv[1], pv[2], pv[3]);
        *(uint2*)(hI + off) = make_uint2(f2h2(o[i][0], o[i][1]), f2h2(o[i][2], o[i][3]));
    }
    block_reduce_store(0.f, accn, &pd[im * 64 + bid], &pn[im * 64 + bid], tid);
}

// Iterations 1..8: unconditional TV step, snapshot write, partials k=it.
__global__ __launch_bounds__(256, 4) void tv_stepN(
    const __half* __restrict__ imgh, const float* __restrict__ weight,
    const uint32_t* __restrict__ pt_in, uint32_t* __restrict__ pt_out,
    float* __restrict__ pd, float* __restrict__ pn, int it)
{
    const int im = blockIdx.z;
    const int bid = blockIdx.y * 8 + blockIdx.x;
    const float w = weight[im / CCH];
    const float tw = TAU / w;
    const int x0 = blockIdx.x * 64, y0 = blockIdx.y * 64;
    const size_t ibase = (size_t)im * HH * WW;
    const __half* hI = imgh + ibase;
    const uint32_t* pinI = pt_in + ibase;
    uint32_t* poutI = pt_out + ibase;
    const int tid = threadIdx.x;
    const int tx = tid & 15, ry = tid >> 4;
    const int gx = x0 + 4 * tx;

    __shared__ float s[65][68];
    uint32_t c[4][4];
    float o[4][4], imv4[4][4];

    #pragma unroll
    for (int i = 0; i < 4; ++i) {
        int ey = ry + 16 * i, gy = y0 + ey;
        size_t off = (size_t)gy * WW + gx;
        uint4 cv = *(const uint4*)(pinI + off);
        uint4 uv = make_uint4(0u, 0u, 0u, 0u);
        if (gy > 0) uv = *(const uint4*)(pinI + off - WW);
        uint32_t lf = (gx > 0) ? pinI[off - 1] : 0u;
        uint2 hh = *(const uint2*)(hI + off);
        c[i][0] = cv.x; c[i][1] = cv.y; c[i][2] = cv.z; c[i][3] = cv.w;
        uint32_t uu[4] = {uv.x, uv.y, uv.z, uv.w};
        uint32_t lt[4] = {lf, cv.x, cv.y, cv.z};
        float2 ia = h2f(hh.x), ib = h2f(hh.y);
        imv4[i][0] = ia.x; imv4[i][1] = ia.y; imv4[i][2] = ib.x; imv4[i][3] = ib.y;
        #pragma unroll
        for (int j = 0; j < 4; ++j) {
            float2 cf = h2f(c[i][j]);
            o[i][j] = imv4[i][j] + (-(cf.x + cf.y) + h2f(uu[j]).x + h2f(lt[j]).y);
        }
        *(float4*)&s[ey][4 * tx] = make_float4(o[i][0], o[i][1], o[i][2], o[i][3]);
    }
    if (tx == 15 && x0 + 64 < WW) {
        #pragma unroll
        for (int i = 0; i < 4; ++i) {
            int ey = ry + 16 * i, gy = y0 + ey;
            size_t off = (size_t)gy * WW + x0 + 64;
            uint32_t c2 = pinI[off];
            uint32_t u2 = (gy > 0) ? pinI[off - WW] : 0u;
            float2 cf = h2f(c2);
            s[ey][64] = __half2float(hI[off]) +
                        (-(cf.x + cf.y) + h2f(u2).x + h2f(c[i][3]).y);
        }
    }
    if (ry == 0 && y0 + 64 < HH) {
        int gy = y0 + 64;
        size_t off = (size_t)gy * WW + gx;
        uint4 cv = *(const uint4*)(pinI + off);
        uint4 uv = *(const uint4*)(pinI + off - WW);
        uint32_t lf = (gx > 0) ? pinI[off - 1] : 0u;
        uint2 hh = *(const uint2*)(hI + off);
        float2 ia = h2f(hh.x), ib = h2f(hh.y);
        float imv[4] = {ia.x, ia.y, ib.x, ib.y};
        uint32_t cc[4] = {cv.x, cv.y, cv.z, cv.w};
        uint32_t uu[4] = {uv.x, uv.y, uv.z, uv.w};
        uint32_t lt[4] = {lf, cv.x, cv.y, cv.z};
        float ob[4];
        #pragma unroll
        for (int j = 0; j < 4; ++j) {
            float2 cf = h2f(cc[j]);
            ob[j] = imv[j] + (-(cf.x + cf.y) + h2f(uu[j]).x + h2f(lt[j]).y);
        }
        *(float4*)&s[64][4 * tx] = make_float4(ob[0], ob[1], ob[2], ob[3]);
    }
    __syncthreads();

    float accd = 0.f, accn = 0.f;
    #pragma unroll
    for (int i = 0; i < 4; ++i) {
        int ey = ry + 16 * i, gy = y0 + ey;
        float4 dn = *(float4*)&s[ey + 1][4 * tx];
        float rt_sh = __shfl_down(o[i][0], 1, 64);
        float rt = (tx == 15) ? s[ey][64] : rt_sh;
        float dnv[4] = {dn.x, dn.y, dn.z, dn.w};
        uint32_t pv[4];
        #pragma unroll
        for (int j = 0; j < 4; ++j) {
            float ov = o[i][j];
            float g0 = (gy < HH - 1) ? dnv[j] - ov : 0.f;
            float rn = (j < 3) ? o[i][j + 1] : rt;
            float g1 = (gx + j < WW - 1) ? rn - ov : 0.f;
            float ss2 = g0 * g0 + g1 * g1;
            float nrm = (ss2 > 0.f) ? sqrtf(ss2) : 0.f;
            accn += nrm;
            float dtv = ov - imv4[i][j];
            accd += dtv * dtv;
            float inv = 1.f / (1.f + tw * nrm);
            float2 cf = h2f(c[i][j]);
            pv[j] = f2h2((cf.x - TAU * g0) * inv, (cf.y - TAU * g1) * inv);
        }
        *(uint4*)(poutI + (size_t)gy * WW + gx) = make_uint4(pv[0], pv[1], pv[2], pv[3]);
    }
    block_reduce_store(accd, accn,
                       &pd[it * NIMG * 64 + im * 64 + bid],
                       &pn[it * NIMG * 64 + im * 64 + bid], tid);
}

// Final: replay energy history once, pick the snapshot, write out.
// kf = first i in [1..8] with |E_{i-1}-E_i| < eps*E0; out = imgh + div(pt[kf-1]),
// else (kf=9 or never) out = imgh + div(pt[8]) -- identical by reference semantics.
__global__ __launch_bounds__(256, 4) void tv_final(
    const __half* __restrict__ imgh, const float* __restrict__ weight,
    const uint32_t* __restrict__ ptbase, float* __restrict__ out,
    const float* __restrict__ pd, const float* __restrict__ pn)
{
    const int im = blockIdx.z;
    const float w = weight[im / CCH];
    const int x0 = blockIdx.x * 64, y0 = blockIdx.y * 64;
    const size_t ibase = (size_t)im * HH * WW;
    const int tid = threadIdx.x;
    const int tx = tid & 15, ry = tid >> 4;
    const int gx = x0 + 4 * tx;

    __shared__ int sKf;
    if (tid < 64) {
        float n0 = pn[im * 64 + tid];
        for (int off = 32; off > 0; off >>= 1) n0 += __shfl_down(n0, off, 64);
        float E0 = w * __shfl(n0, 0, 64) / NUMEL;
        float Eprev = E0;
        int kf = -1;
        for (int k = 1; k <= 8; ++k) {
            float d = pd[k * NIMG * 64 + im * 64 + tid];
            float n = pn[k * NIMG * 64 + im * 64 + tid];
            for (int off = 32; off > 0; off >>= 1) {
                d += __shfl_down(d, off, 64);
                n += __shfl_down(n, off, 64);
            }
            float Ek = (__shfl(d, 0, 64) + w * __shfl(n, 0, 64)) / NUMEL;
            if (fabsf(Eprev - Ek) < TVEPS * E0) { kf = k; break; }
            Eprev = Ek;
        }
        if (tid == 0) sKf = kf;
    }
    __syncthreads();
    const int kf = sKf;
    const int ku = (kf >= 1) ? (kf - 1) : 8;

    const uint32_t* p = ptbase + (size_t)ku * PTELEMS + ibase;
    const __half* hI = imgh + ibase;
    float* outI = out + ibase;
    #pragma unroll
    for (int i = 0; i < 4; ++i) {
        int gy = y0 + ry + 16 * i;
        size_t off = (size_t)gy * WW + gx;
        uint4 cv = *(const uint4*)(p + off);
        uint4 uv = make_uint4(0u, 0u, 0u, 0u);
        if (gy > 0) uv = *(const uint4*)(p + off - WW);
        uint32_t lf = (gx > 0) ? p[off - 1] : 0u;
        uint2 hh = *(const uint2*)(hI + off);
        float2 ia = h2f(hh.x), ib = h2f(hh.y);
        float imv[4] = {ia.x, ia.y, ib.x, ib.y};
        uint32_t cc[4] = {cv.x, cv.y, cv.z, cv.w};
        uint32_t uu[4] = {uv.x, uv.y, uv.z, uv.w};
        uint32_t lt[4] = {lf, cv.x, cv.y, cv.z};
        float r[4];
        #pragma unroll
        for (int j = 0; j < 4; ++j) {
            float2 cf = h2f(cc[j]);
            r[j] = imv[j] + (-(cf.x + cf.y) + h2f(uu[j]).x + h2f(lt[j]).y);
        }
        *(float4*)(outI + off) = make_float4(r[0], r[1], r[2], r[3]);
    }
}

extern "C" void kernel_launch(void* const* d_in, const int* in_sizes, int n_in,
                              void* d_out, int out_size, void* d_ws, size_t ws_size,
                              hipStream_t stream)
{
    const float* img = (const float*)d_in[0];
    const float* weight = (const float*)d_in[1];
    float* out = (float*)d_out;
    float* pd = (float*)((char*)d_ws + 0);
    float* pn = (float*)((char*)d_ws + 65536);
    __half* imgh = (__half*)((char*)d_ws + 131072);
    uint32_t* ptbase = (uint32_t*)((char*)d_ws + 12713984);

    dim3 grid(8, 8, NIMG);
    dim3 block(256);

    tv_step0<<<grid, block, 0, stream>>>(img, weight, imgh, ptbase, pd, pn);
    for (int it = 1; it <= 8; ++it) {
        uint32_t* pin  = ptbase + (size_t)(it - 1) * PTELEMS;
        uint32_t* pout = ptbase + (size_t)it * PTELEMS;
        tv_stepN<<<grid, block, 0, stream>>>(imgh, weight, pin, pout, pd, pn, it);
    }
    tv_final<<<grid, block, 0, stream>>>(imgh, weight, ptbase, out, pd, pn);
}